// Round 10
// baseline (223.259 us; speedup 1.0000x reference)
//
#include <hip/hip_runtime.h>
#include <math.h>
#include <stdint.h>

#define NLEV 16
#define TSIZE (1u << 19)
#define NB 4096
#define NS 48
#define NPTS (NB * NS)

typedef __attribute__((ext_vector_type(8))) short short8;
typedef __attribute__((ext_vector_type(4))) float f32x4;

struct Scales { float s[NLEV]; };

__device__ __forceinline__ uint32_t hash3(uint32_t x, uint32_t y, uint32_t z) {
    return (x ^ (y * 2654435761u) ^ (z * 805459861u)) & (TSIZE - 1u);
}

__device__ __forceinline__ float sigmoidf(float v) {
    return 1.0f / (1.0f + expf(-v));
}

// fp32 -> bf16 (round to nearest even), raw ushort bits
__device__ __forceinline__ ushort f2b(float f) {
    union { float f; uint32_t u; } v; v.f = f;
    uint32_t r = (v.u + 0x7FFFu + ((v.u >> 16) & 1u)) >> 16;
    return (ushort)r;
}

// Compiler fence + LDS drain: makes per-wave LDS write->read chaining sound
// (round-6 race was COMPILER reordering of ds_read before ds_write; HW DS is
// in-order per wave, lgkmcnt(0) drains outstanding DS ops).
#define LDS_FENCE() asm volatile("s_waitcnt lgkmcnt(0)" ::: "memory")

#define MFMA16(a, b, c) __builtin_amdgcn_mfma_f32_16x16x32_bf16((a), (b), (c), 0, 0, 0)

// prep: one block builds the 20-fragment weight bank (64 lanes x 8 bf16 per
// fragment, lane-ordered so a wave loads one fragment as a coalesced dwordx4):
//   f0..3 W1^T | f4..5 W2^T | f6..9 H1^T | f10..17 H2^T (nt*2+kk) |
//   f18..19 H3^T (cols>=3 zero)
__global__ __launch_bounds__(256) void prep_bank_kernel(
    const float* __restrict__ w1, const float* __restrict__ w2,
    const float* __restrict__ h1, const float* __restrict__ h2,
    const float* __restrict__ h3,
    ushort* __restrict__ bank)
{
    for (int idx = threadIdx.x; idx < 20 * 512; idx += 256) {
        const int f    = idx >> 9;
        const int r    = idx & 511;
        const int lane = r >> 3;
        const int j    = r & 7;
        const int l15  = lane & 15;
        const int quad = lane >> 4;
        const int k8   = quad * 8 + j;
        float val;
        if (f < 4) {
            val = w1[k8 * 64 + f * 16 + l15];
        } else if (f < 6) {
            val = w2[((f - 4) * 32 + k8) * 16 + l15];
        } else if (f < 10) {
            val = h1[k8 * 64 + (f - 6) * 16 + l15];
        } else if (f < 18) {
            const int t = f - 10, nt = t >> 1, kk = t & 1;
            val = h2[(kk * 32 + k8) * 64 + nt * 16 + l15];
        } else {
            val = (l15 < 3) ? h3[((f - 18) * 32 + k8) * 3 + l15] : 0.0f;
        }
        bank[idx] = f2b(val);
    }
}

// encode: fp32 table, 2-D grid with y = level. Dispatch order (x fastest)
// sweeps one 4 MB level slice at a time across the whole GPU — the slice
// fits per-XCD L2 (measured: this layout beats the 1-D bid&15 "XCD pinning"
// guess by ~12%; workgroup->XCD mapping is undefined, dispatch ORDER
// locality is what's real). Request-rate bound: 25.2M random gathers at
// ~16 req/cy/XCD => ~82 us floor.
__global__ __launch_bounds__(256) void encode_kernel(
    const float* __restrict__ positions,
    const float* __restrict__ c2w,
    const float* __restrict__ table,
    uint32_t* __restrict__ enc_ws,
    Scales sc)
{
    const int l = blockIdx.y;               // wave-uniform level
    const int p = blockIdx.x * 256 + threadIdx.x;
    const int b = p / NS;

    const float* M = c2w + b * 12;
    const float px = positions[3 * p + 0];
    const float py = positions[3 * p + 1];
    const float pz = positions[3 * p + 2];
    const float dx = px - M[3], dy = py - M[7], dz = pz - M[11];
    float qx = M[0] * dx + M[4] * dy + M[8] * dz;
    float qy = M[1] * dx + M[5] * dy + M[9] * dz;
    float qz = M[2] * dx + M[6] * dy + M[10] * dz;
    qx = (qx + 1.0f) * 0.5f;
    qy = (qy + 1.0f) * 0.5f;
    qz = (qz + 1.0f) * 0.5f;
    const bool sel = (qx > 0.0f) && (qx < 1.0f) &&
                     (qy > 0.0f) && (qy < 1.0f) &&
                     (qz > 0.0f) && (qz < 1.0f);
    if (!sel) { qx = 0.0f; qy = 0.0f; qz = 0.0f; }

    const float s = sc.s[l];
    const float sx = qx * s, sy = qy * s, sz = qz * s;
    const float fx = floorf(sx), fy = floorf(sy), fz = floorf(sz);
    const float cx = ceilf(sx),  cy = ceilf(sy),  cz = ceilf(sz);
    const float ox = sx - fx, oy = sy - fy, oz = sz - fz;
    const uint32_t fxi = (uint32_t)fx, fyi = (uint32_t)fy, fzi = (uint32_t)fz;
    const uint32_t cxi = (uint32_t)cx, cyi = (uint32_t)cy, czi = (uint32_t)cz;

    const float2* tab = (const float2*)table + (uint32_t)l * TSIZE;
    const float2 g0 = tab[hash3(cxi, cyi, czi)];
    const float2 g1 = tab[hash3(cxi, fyi, czi)];
    const float2 g2 = tab[hash3(fxi, fyi, czi)];
    const float2 g3 = tab[hash3(fxi, cyi, czi)];
    const float2 g4 = tab[hash3(cxi, cyi, fzi)];
    const float2 g5 = tab[hash3(cxi, fyi, fzi)];
    const float2 g6 = tab[hash3(fxi, fyi, fzi)];
    const float2 g7 = tab[hash3(fxi, cyi, fzi)];

    const float omx = 1.0f - ox, omy = 1.0f - oy, omz = 1.0f - oz;
    float f03x = g0.x * ox + g3.x * omx, f03y = g0.y * ox + g3.y * omx;
    float f12x = g1.x * ox + g2.x * omx, f12y = g1.y * ox + g2.y * omx;
    float f56x = g5.x * ox + g6.x * omx, f56y = g5.y * ox + g6.y * omx;
    float f47x = g4.x * ox + g7.x * omx, f47y = g4.y * ox + g7.y * omx;
    float ax = f03x * oy + f12x * omy, ay = f03y * oy + f12y * omy;
    float bx = f47x * oy + f56x * omy, by = f47y * oy + f56y * omy;
    const float ex = ax * oz + bx * omz;
    const float ey = ay * oz + by * omz;
    enc_ws[l * NPTS + p] = ((uint32_t)f2b(ey) << 16) | (uint32_t)f2b(ex);
}

// tail — MLP + softmax-reduce. One 64-thread wave per batch (48 points
// = 3 MFMA m-tiles). All LDS dataflow is intra-wave (rows 0..47 private to
// the wave) => no __syncthreads anywhere; LDS_FENCE() between stages pins
// the compiler and drains DS. Buffer aliasing (lifetimes are disjoint):
//   bufA: sX (L1 in)   then sU (L3 out)
//   bufB: sA1 (L1 out) then sV (L4 out)
//   bufC: sHIN [SH16|geo] (dead after L3), then sW (softmax weights)
// MFMA layouts (verified m89/m120): A[m=lane&15][k=quad*8+j],
// B[n=lane&15][k=quad*8+j], C/D col=lane&15, row=quad*4+reg.
__global__ __launch_bounds__(64) void tail_kernel(
    const uint32_t* __restrict__ enc_ws,
    const float* __restrict__ densities,
    const float* __restrict__ normals,
    const float* __restrict__ c2w,
    const ushort* __restrict__ bank,
    const float* __restrict__ b1, const float* __restrict__ b2,
    const float* __restrict__ hb1, const float* __restrict__ hb2,
    const float* __restrict__ hb3,
    float* __restrict__ out)
{
    __shared__ ushort bufA[48 * 72];
    __shared__ ushort bufB[48 * 72];
    __shared__ ushort bufC[48 * 40];

    const int bidb = blockIdx.x;       // batch
    const int p0   = bidb * NS;
    const int lane = threadIdx.x;
    const int l15  = lane & 15;
    const int quad = lane >> 4;

    // ---- stage X: 48 pts x 16 levels from level-major enc_ws -> bufA ----
#pragma unroll
    for (int i = 0; i < 12; ++i) {
        const int flat = i * 64 + lane;       // < 768
        const int l = flat / 48;
        const int j = flat - l * 48;
        *(uint32_t*)&bufA[j * 72 + 2 * l] = enc_ws[l * NPTS + p0 + j];
    }

    // ---- SH16 (identical for the whole batch): each lane keeps sh[l15] ----
    {
        const float* M = c2w + bidb * 12;
        const float n0 = normals[3 * bidb + 0];
        const float n1 = normals[3 * bidb + 1];
        const float n2 = normals[3 * bidb + 2];
        float x = M[0] * n0 + M[4] * n1 + M[8] * n2;
        float y = M[1] * n0 + M[5] * n1 + M[9] * n2;
        float z = M[2] * n0 + M[6] * n1 + M[10] * n2;
        x = (x + 1.0f) * 0.5f;
        y = (y + 1.0f) * 0.5f;
        z = (z + 1.0f) * 0.5f;
        const float xx = x * x, yy = y * y, zz = z * z;
        float v = 0.28209479177387814f;
        v = (l15 == 1)  ? -0.48860251190291987f * y : v;
        v = (l15 == 2)  ?  0.48860251190291987f * z : v;
        v = (l15 == 3)  ? -0.48860251190291987f * x : v;
        v = (l15 == 4)  ?  1.0925484305920792f * x * y : v;
        v = (l15 == 5)  ? -1.0925484305920792f * y * z : v;
        v = (l15 == 6)  ?  0.94617469575756f * zz - 0.31539156525252f : v;
        v = (l15 == 7)  ? -1.0925484305920792f * x * z : v;
        v = (l15 == 8)  ?  0.5462742152960396f * (xx - yy) : v;
        v = (l15 == 9)  ?  0.5900435899266435f * y * (3.0f * xx - yy) : v;
        v = (l15 == 10) ?  2.890611442640554f * x * y * z : v;
        v = (l15 == 11) ?  0.4570457994644657f * y * (5.0f * zz - 1.0f) : v;
        v = (l15 == 12) ?  0.37317633259011546f * z * (5.0f * zz - 3.0f) : v;
        v = (l15 == 13) ?  0.4570457994644657f * x * (5.0f * zz - 1.0f) : v;
        v = (l15 == 14) ?  1.445305721320277f * z * (xx - yy) : v;
        v = (l15 == 15) ?  0.5900435899266435f * x * (xx - 3.0f * yy) : v;
        const ushort shb = f2b(v);
#pragma unroll
        for (int i = 0; i < 12; ++i) {
            bufC[(i * 4 + quad) * 40 + l15] = shb;   // SH cols for all 48 rows
        }
    }

    // ---- per-lane biases ----
    float b1v[4], hb1v[4], hb2v[4];
#pragma unroll
    for (int nt = 0; nt < 4; ++nt) {
        b1v[nt]  = b1[nt * 16 + l15];
        hb1v[nt] = hb1[nt * 16 + l15];
        hb2v[nt] = hb2[nt * 16 + l15];
    }
    const float b2v  = b2[l15];
    const float hb3v = (l15 < 3) ? hb3[l15] : 0.0f;

    const ushort* fb = bank + lane * 8;
#define FRAG(f) (*(const short8*)(fb + (f) * 512))

    const f32x4 zero = {0.0f, 0.0f, 0.0f, 0.0f};
    LDS_FENCE();

    // ---- L1: X(32) @ W1 -> 64, +b1, relu -> bufB ----
    {
        short8 w[4];
#pragma unroll
        for (int nt = 0; nt < 4; ++nt) w[nt] = FRAG(nt);
        f32x4 c[3][4];
#pragma unroll
        for (int t = 0; t < 3; ++t) {
            const short8 a = *(const short8*)&bufA[(16 * t + l15) * 72 + quad * 8];
#pragma unroll
            for (int nt = 0; nt < 4; ++nt) c[t][nt] = MFMA16(a, w[nt], zero);
        }
        LDS_FENCE();
#pragma unroll
        for (int t = 0; t < 3; ++t)
#pragma unroll
            for (int nt = 0; nt < 4; ++nt)
#pragma unroll
                for (int r = 0; r < 4; ++r) {
                    const float v = fmaxf(c[t][nt][r] + b1v[nt], 0.0f);
                    bufB[(16 * t + quad * 4 + r) * 72 + nt * 16 + l15] = f2b(v);
                }
    }
    LDS_FENCE();

    // ---- L2: A1(64) @ W2 -> 16 geo, +b2, relu -> bufC cols 16..31 ----
    {
        const short8 w0 = FRAG(4), w1f = FRAG(5);
#pragma unroll
        for (int t = 0; t < 3; ++t) {
            const short8 a0 = *(const short8*)&bufB[(16 * t + l15) * 72 + quad * 8];
            const short8 a1 = *(const short8*)&bufB[(16 * t + l15) * 72 + 32 + quad * 8];
            f32x4 c = MFMA16(a0, w0, zero);
            c = MFMA16(a1, w1f, c);
#pragma unroll
            for (int r = 0; r < 4; ++r) {
                const float v = fmaxf(c[r] + b2v, 0.0f);
                bufC[(16 * t + quad * 4 + r) * 40 + 16 + l15] = f2b(v);
            }
        }
    }
    LDS_FENCE();

    // ---- L3: HIN(32) @ H1 -> 64, +hb1, relu -> bufA (sU) ----
    {
        short8 w[4];
#pragma unroll
        for (int nt = 0; nt < 4; ++nt) w[nt] = FRAG(6 + nt);
        f32x4 c[3][4];
#pragma unroll
        for (int t = 0; t < 3; ++t) {
            const short8 a = *(const short8*)&bufC[(16 * t + l15) * 40 + quad * 8];
#pragma unroll
            for (int nt = 0; nt < 4; ++nt) c[t][nt] = MFMA16(a, w[nt], zero);
        }
        LDS_FENCE();   // bufA reuse: X-reads (L1) long done for this wave
#pragma unroll
        for (int t = 0; t < 3; ++t)
#pragma unroll
            for (int nt = 0; nt < 4; ++nt)
#pragma unroll
                for (int r = 0; r < 4; ++r) {
                    const float v = fmaxf(c[t][nt][r] + hb1v[nt], 0.0f);
                    bufA[(16 * t + quad * 4 + r) * 72 + nt * 16 + l15] = f2b(v);
                }
    }
    LDS_FENCE();

    // ---- L4: U(64) @ H2 -> 64, +hb2, relu -> bufB (sV) ----
    {
        short8 w[8];
#pragma unroll
        for (int f = 0; f < 8; ++f) w[f] = FRAG(10 + f);
        f32x4 c[3][4];
#pragma unroll
        for (int t = 0; t < 3; ++t) {
            const short8 a0 = *(const short8*)&bufA[(16 * t + l15) * 72 + quad * 8];
            const short8 a1 = *(const short8*)&bufA[(16 * t + l15) * 72 + 32 + quad * 8];
#pragma unroll
            for (int nt = 0; nt < 4; ++nt) {
                f32x4 u = MFMA16(a0, w[nt * 2], zero);
                c[t][nt] = MFMA16(a1, w[nt * 2 + 1], u);
            }
        }
        LDS_FENCE();
#pragma unroll
        for (int t = 0; t < 3; ++t)
#pragma unroll
            for (int nt = 0; nt < 4; ++nt)
#pragma unroll
                for (int r = 0; r < 4; ++r) {
                    const float v = fmaxf(c[t][nt][r] + hb2v[nt], 0.0f);
                    bufB[(16 * t + quad * 4 + r) * 72 + nt * 16 + l15] = f2b(v);
                }
    }
    LDS_FENCE();

    // ---- L5: V(64) @ H3 -> 3 (cols>=3 are zero weights) ----
    f32x4 rgbc[3];
    {
        const short8 w0 = FRAG(18), w1f = FRAG(19);
#pragma unroll
        for (int t = 0; t < 3; ++t) {
            const short8 a0 = *(const short8*)&bufB[(16 * t + l15) * 72 + quad * 8];
            const short8 a1 = *(const short8*)&bufB[(16 * t + l15) * 72 + 32 + quad * 8];
            f32x4 c = MFMA16(a0, w0, zero);
            rgbc[t] = MFMA16(a1, w1f, c);
        }
    }
#undef FRAG

    // ---- softmax over the batch's 48 densities (wave shuffles) ----
    const float d = (lane < NS) ? densities[p0 + lane] : -INFINITY;
    float m = d;
#pragma unroll
    for (int off = 32; off > 0; off >>= 1) m = fmaxf(m, __shfl_xor(m, off));
    const float e = expf(d - m);              // -inf -> 0 for lanes >= 48
    float sum = e;
#pragma unroll
    for (int off = 32; off > 0; off >>= 1) sum += __shfl_xor(sum, off);
    const float wgt = e / sum;

    float* sW = (float*)bufC;                 // bufC dead after L3
    LDS_FENCE();
    if (lane < NS) sW[lane] = wgt;
    LDS_FENCE();

    // ---- weighted sum of sigmoid(rgb): rows held as C-layout frags ----
    float acc = 0.0f;
#pragma unroll
    for (int t = 0; t < 3; ++t)
#pragma unroll
        for (int r = 0; r < 4; ++r) {
            const int row = 16 * t + quad * 4 + r;
            acc += sW[row] * sigmoidf(rgbc[t][r] + hb3v);
        }
    // butterfly over quads (same l15 in lanes {l15, 16+l15, 32+l15, 48+l15})
    acc += __shfl_xor(acc, 16);
    acc += __shfl_xor(acc, 32);
    if (lane < 3) out[bidb * 3 + lane] = acc;
}

extern "C" void kernel_launch(void* const* d_in, const int* in_sizes, int n_in,
                              void* d_out, int out_size, void* d_ws, size_t ws_size,
                              hipStream_t stream) {
    const float* positions = (const float*)d_in[0];
    const float* densities = (const float*)d_in[1];
    const float* normals   = (const float*)d_in[2];
    const float* c2w       = (const float*)d_in[3];
    const float* table     = (const float*)d_in[4];
    const float* w1  = (const float*)d_in[5];
    const float* b1  = (const float*)d_in[6];
    const float* w2  = (const float*)d_in[7];
    const float* b2  = (const float*)d_in[8];
    const float* h1  = (const float*)d_in[9];
    const float* hb1 = (const float*)d_in[10];
    const float* h2  = (const float*)d_in[11];
    const float* hb2 = (const float*)d_in[12];
    const float* h3  = (const float*)d_in[13];
    const float* hb3 = (const float*)d_in[14];
    float* out = (float*)d_out;

    // ws layout: bank (20 KB) | enc (NLEV*NPTS u32 = 12.6 MB)
    ushort*   bank   = (ushort*)d_ws;
    uint32_t* enc_ws = (uint32_t*)((char*)d_ws + 20 * 1024);

    Scales sc;
    const double growth = exp((log(2048.0) - log(16.0)) / 15.0);
    for (int i = 0; i < NLEV; ++i)
        sc.s[i] = (float)floor(16.0 * pow(growth, (double)i));

    prep_bank_kernel<<<1, 256, 0, stream>>>(w1, w2, h1, h2, h3, bank);
    encode_kernel<<<dim3(NPTS / 256, NLEV), 256, 0, stream>>>(
        positions, c2w, table, enc_ws, sc);
    tail_kernel<<<NB, 64, 0, stream>>>(
        enc_ws, densities, normals, c2w, bank, b1, b2, hb1, hb2, hb3, out);
}

// Round 11
// 222.606 us; speedup vs baseline: 1.0029x; 1.0029x over previous
//
#include <hip/hip_runtime.h>
#include <math.h>
#include <stdint.h>

#define NLEV 16
#define TSIZE (1u << 19)
#define NB 4096
#define NS 48
#define NPTS (NB * NS)

typedef __attribute__((ext_vector_type(8))) short short8;
typedef __attribute__((ext_vector_type(4))) float f32x4;

struct Scales { float s[NLEV]; };

__device__ __forceinline__ uint32_t hash3(uint32_t x, uint32_t y, uint32_t z) {
    return (x ^ (y * 2654435761u) ^ (z * 805459861u)) & (TSIZE - 1u);
}

__device__ __forceinline__ float sigmoidf(float v) {
    return 1.0f / (1.0f + expf(-v));
}

// fp32 -> bf16 (round to nearest even), raw ushort bits
__device__ __forceinline__ ushort f2b(float f) {
    union { float f; uint32_t u; } v; v.f = f;
    uint32_t r = (v.u + 0x7FFFu + ((v.u >> 16) & 1u)) >> 16;
    return (ushort)r;
}

// Compiler fence + LDS drain (round-6 lesson: HW DS is in-order per wave but
// the COMPILER may reorder ds_read/ds_write across cross-lane dataflow it
// cannot see; the asm memory clobber pins ordering, lgkmcnt(0) drains).
#define LDS_FENCE() asm volatile("s_waitcnt lgkmcnt(0)" ::: "memory")

#define MFMA16(a, b, c) __builtin_amdgcn_mfma_f32_16x16x32_bf16((a), (b), (c), 0, 0, 0)

// prep: one block builds the 20-fragment weight bank (64 lanes x 8 bf16 per
// fragment, lane-ordered so a wave loads one fragment as a coalesced dwordx4):
//   f0..3 W1^T | f4..5 W2^T | f6..9 H1^T | f10..17 H2^T (nt*2+kk) |
//   f18..19 H3^T (cols>=3 zero)
__global__ __launch_bounds__(256) void prep_bank_kernel(
    const float* __restrict__ w1, const float* __restrict__ w2,
    const float* __restrict__ h1, const float* __restrict__ h2,
    const float* __restrict__ h3,
    ushort* __restrict__ bank)
{
    for (int idx = threadIdx.x; idx < 20 * 512; idx += 256) {
        const int f    = idx >> 9;
        const int r    = idx & 511;
        const int lane = r >> 3;
        const int j    = r & 7;
        const int l15  = lane & 15;
        const int quad = lane >> 4;
        const int k8   = quad * 8 + j;
        float val;
        if (f < 4) {
            val = w1[k8 * 64 + f * 16 + l15];
        } else if (f < 6) {
            val = w2[((f - 4) * 32 + k8) * 16 + l15];
        } else if (f < 10) {
            val = h1[k8 * 64 + (f - 6) * 16 + l15];
        } else if (f < 18) {
            const int t = f - 10, nt = t >> 1, kk = t & 1;
            val = h2[(kk * 32 + k8) * 64 + nt * 16 + l15];
        } else {
            val = (l15 < 3) ? h3[((f - 18) * 32 + k8) * 3 + l15] : 0.0f;
        }
        bank[idx] = f2b(val);
    }
}

// encode: fp32 table, 2-D grid with y = level. Dispatch order (x fastest)
// sweeps one 4 MB level slice at a time across the whole GPU — dispatch-ORDER
// temporal locality (the slice fits per-XCD L2). Request-rate bound:
// 25.2M random lane-gathers at ~16 req/cy/XCD => ~82 us floor (measured:
// halving table bytes in R8 changed nothing — request count, not bytes).
__global__ __launch_bounds__(256) void encode_kernel(
    const float* __restrict__ positions,
    const float* __restrict__ c2w,
    const float* __restrict__ table,
    uint32_t* __restrict__ enc_ws,
    Scales sc)
{
    const int l = blockIdx.y;               // wave-uniform level
    const int p = blockIdx.x * 256 + threadIdx.x;
    const int b = p / NS;

    const float* M = c2w + b * 12;
    const float px = positions[3 * p + 0];
    const float py = positions[3 * p + 1];
    const float pz = positions[3 * p + 2];
    const float dx = px - M[3], dy = py - M[7], dz = pz - M[11];
    float qx = M[0] * dx + M[4] * dy + M[8] * dz;
    float qy = M[1] * dx + M[5] * dy + M[9] * dz;
    float qz = M[2] * dx + M[6] * dy + M[10] * dz;
    qx = (qx + 1.0f) * 0.5f;
    qy = (qy + 1.0f) * 0.5f;
    qz = (qz + 1.0f) * 0.5f;
    const bool sel = (qx > 0.0f) && (qx < 1.0f) &&
                     (qy > 0.0f) && (qy < 1.0f) &&
                     (qz > 0.0f) && (qz < 1.0f);
    if (!sel) { qx = 0.0f; qy = 0.0f; qz = 0.0f; }

    const float s = sc.s[l];
    const float sx = qx * s, sy = qy * s, sz = qz * s;
    const float fx = floorf(sx), fy = floorf(sy), fz = floorf(sz);
    const float cx = ceilf(sx),  cy = ceilf(sy),  cz = ceilf(sz);
    const float ox = sx - fx, oy = sy - fy, oz = sz - fz;
    const uint32_t fxi = (uint32_t)fx, fyi = (uint32_t)fy, fzi = (uint32_t)fz;
    const uint32_t cxi = (uint32_t)cx, cyi = (uint32_t)cy, czi = (uint32_t)cz;

    const float2* tab = (const float2*)table + (uint32_t)l * TSIZE;
    const float2 g0 = tab[hash3(cxi, cyi, czi)];
    const float2 g1 = tab[hash3(cxi, fyi, czi)];
    const float2 g2 = tab[hash3(fxi, fyi, czi)];
    const float2 g3 = tab[hash3(fxi, cyi, czi)];
    const float2 g4 = tab[hash3(cxi, cyi, fzi)];
    const float2 g5 = tab[hash3(cxi, fyi, fzi)];
    const float2 g6 = tab[hash3(fxi, fyi, fzi)];
    const float2 g7 = tab[hash3(fxi, cyi, fzi)];

    const float omx = 1.0f - ox, omy = 1.0f - oy, omz = 1.0f - oz;
    float f03x = g0.x * ox + g3.x * omx, f03y = g0.y * ox + g3.y * omx;
    float f12x = g1.x * ox + g2.x * omx, f12y = g1.y * ox + g2.y * omx;
    float f56x = g5.x * ox + g6.x * omx, f56y = g5.y * ox + g6.y * omx;
    float f47x = g4.x * ox + g7.x * omx, f47y = g4.y * ox + g7.y * omx;
    float ax = f03x * oy + f12x * omy, ay = f03y * oy + f12y * omy;
    float bx = f47x * oy + f56x * omy, by = f47y * oy + f56y * omy;
    const float ex = ax * oz + bx * omz;
    const float ey = ay * oz + by * omz;
    enc_ws[l * NPTS + p] = ((uint32_t)f2b(ey) << 16) | (uint32_t)f2b(ex);
}

// tail — MLP + softmax-reduce, one 64-thread wave per batch (48 pts = 3
// m-tiles). Two aliased LDS buffers (13.8 KB -> 11 blocks/CU):
//   bufA cols 0..31 = X       (dead after L1)
//   bufA cols 32..47 = SH16, cols 48..63 = geo  (HIN; dead after L3)
//   bufA cols 0..63 = V       (L4 out, read by L5)
//   bufB cols 0..63 = A1 (L1 out) -> U (L3 out) -> sW floats (softmax)
// 7 fences, one per genuine LDS write->read edge (compiler-pinning; HW DS is
// per-wave in-order). MFMA layouts (verified m89/m120):
//   A[m=lane&15][k=quad*8+j], B[n=lane&15][k=quad*8+j],
//   C/D col=lane&15, row=quad*4+reg.
__global__ __launch_bounds__(64) void tail_kernel(
    const uint32_t* __restrict__ enc_ws,
    const float* __restrict__ densities,
    const float* __restrict__ normals,
    const float* __restrict__ c2w,
    const ushort* __restrict__ bank,
    const float* __restrict__ b1, const float* __restrict__ b2,
    const float* __restrict__ hb1, const float* __restrict__ hb2,
    const float* __restrict__ hb3,
    float* __restrict__ out)
{
    __shared__ ushort bufA[48 * 72];
    __shared__ ushort bufB[48 * 72];

    const int bidb = blockIdx.x;       // batch
    const int p0   = bidb * NS;
    const int lane = threadIdx.x;
    const int l15  = lane & 15;
    const int quad = lane >> 4;

    // ---- stage X: 6 dwordx2 loads/lane (point-pairs at one level) ----
#pragma unroll
    for (int i = 0; i < 6; ++i) {
        const int flat = i * 64 + lane;       // < 384 tasks = 16 lev x 24 pairs
        const int l  = flat / 24;
        const int j  = (flat - l * 24) * 2;
        const uint2 v = *(const uint2*)&enc_ws[l * NPTS + p0 + j];
        *(uint32_t*)&bufA[j * 72 + 2 * l]       = v.x;
        *(uint32_t*)&bufA[(j + 1) * 72 + 2 * l] = v.y;
    }

    // ---- SH16 (batch-uniform): lane computes sh[l15], all 48 rows ----
    {
        const float* M = c2w + bidb * 12;
        const float n0 = normals[3 * bidb + 0];
        const float n1 = normals[3 * bidb + 1];
        const float n2 = normals[3 * bidb + 2];
        float x = M[0] * n0 + M[4] * n1 + M[8] * n2;
        float y = M[1] * n0 + M[5] * n1 + M[9] * n2;
        float z = M[2] * n0 + M[6] * n1 + M[10] * n2;
        x = (x + 1.0f) * 0.5f;
        y = (y + 1.0f) * 0.5f;
        z = (z + 1.0f) * 0.5f;
        const float xx = x * x, yy = y * y, zz = z * z;
        float v = 0.28209479177387814f;
        v = (l15 == 1)  ? -0.48860251190291987f * y : v;
        v = (l15 == 2)  ?  0.48860251190291987f * z : v;
        v = (l15 == 3)  ? -0.48860251190291987f * x : v;
        v = (l15 == 4)  ?  1.0925484305920792f * x * y : v;
        v = (l15 == 5)  ? -1.0925484305920792f * y * z : v;
        v = (l15 == 6)  ?  0.94617469575756f * zz - 0.31539156525252f : v;
        v = (l15 == 7)  ? -1.0925484305920792f * x * z : v;
        v = (l15 == 8)  ?  0.5462742152960396f * (xx - yy) : v;
        v = (l15 == 9)  ?  0.5900435899266435f * y * (3.0f * xx - yy) : v;
        v = (l15 == 10) ?  2.890611442640554f * x * y * z : v;
        v = (l15 == 11) ?  0.4570457994644657f * y * (5.0f * zz - 1.0f) : v;
        v = (l15 == 12) ?  0.37317633259011546f * z * (5.0f * zz - 3.0f) : v;
        v = (l15 == 13) ?  0.4570457994644657f * x * (5.0f * zz - 1.0f) : v;
        v = (l15 == 14) ?  1.445305721320277f * z * (xx - yy) : v;
        v = (l15 == 15) ?  0.5900435899266435f * x * (xx - 3.0f * yy) : v;
        const ushort shb = f2b(v);
#pragma unroll
        for (int i = 0; i < 12; ++i) {
            bufA[(i * 4 + quad) * 72 + 32 + l15] = shb;
        }
    }

    // ---- per-lane biases ----
    float b1v[4], hb1v[4], hb2v[4];
#pragma unroll
    for (int nt = 0; nt < 4; ++nt) {
        b1v[nt]  = b1[nt * 16 + l15];
        hb1v[nt] = hb1[nt * 16 + l15];
        hb2v[nt] = hb2[nt * 16 + l15];
    }
    const float b2v  = b2[l15];
    const float hb3v = (l15 < 3) ? hb3[l15] : 0.0f;

    const ushort* fb = bank + lane * 8;
#define FRAG(f) (*(const short8*)(fb + (f) * 512))

    const f32x4 zero = {0.0f, 0.0f, 0.0f, 0.0f};
    LDS_FENCE();   // (1) X+SH writes -> L1 reads

    // ---- L1: X(32) @ W1 -> 64, +b1, relu -> bufB (A1) ----
    {
        short8 w[4];
#pragma unroll
        for (int nt = 0; nt < 4; ++nt) w[nt] = FRAG(nt);
        f32x4 c[3][4];
#pragma unroll
        for (int t = 0; t < 3; ++t) {
            const short8 a = *(const short8*)&bufA[(16 * t + l15) * 72 + quad * 8];
#pragma unroll
            for (int nt = 0; nt < 4; ++nt) c[t][nt] = MFMA16(a, w[nt], zero);
        }
#pragma unroll
        for (int t = 0; t < 3; ++t)
#pragma unroll
            for (int nt = 0; nt < 4; ++nt)
#pragma unroll
                for (int r = 0; r < 4; ++r) {
                    const float v = fmaxf(c[t][nt][r] + b1v[nt], 0.0f);
                    bufB[(16 * t + quad * 4 + r) * 72 + nt * 16 + l15] = f2b(v);
                }
    }
    LDS_FENCE();   // (2) L1 writes (bufB) -> L2 reads

    // ---- L2: A1(64) @ W2 -> 16 geo, +b2, relu -> bufA cols 48..63 ----
    {
        const short8 w0 = FRAG(4), w1f = FRAG(5);
#pragma unroll
        for (int t = 0; t < 3; ++t) {
            const short8 a0 = *(const short8*)&bufB[(16 * t + l15) * 72 + quad * 8];
            const short8 a1 = *(const short8*)&bufB[(16 * t + l15) * 72 + 32 + quad * 8];
            f32x4 c = MFMA16(a0, w0, zero);
            c = MFMA16(a1, w1f, c);
#pragma unroll
            for (int r = 0; r < 4; ++r) {
                const float v = fmaxf(c[r] + b2v, 0.0f);
                bufA[(16 * t + quad * 4 + r) * 72 + 48 + l15] = f2b(v);
            }
        }
    }
    LDS_FENCE();   // (3) L2 writes (bufA geo) -> L3 reads; also orders L3's
                   //     bufB writes after L2's bufB reads

    // ---- L3: HIN(32, bufA cols 32..63) @ H1 -> 64, +hb1, relu -> bufB (U) ----
    {
        short8 w[4];
#pragma unroll
        for (int nt = 0; nt < 4; ++nt) w[nt] = FRAG(6 + nt);
        f32x4 c[3][4];
#pragma unroll
        for (int t = 0; t < 3; ++t) {
            const short8 a = *(const short8*)&bufA[(16 * t + l15) * 72 + 32 + quad * 8];
#pragma unroll
            for (int nt = 0; nt < 4; ++nt) c[t][nt] = MFMA16(a, w[nt], zero);
        }
#pragma unroll
        for (int t = 0; t < 3; ++t)
#pragma unroll
            for (int nt = 0; nt < 4; ++nt)
#pragma unroll
                for (int r = 0; r < 4; ++r) {
                    const float v = fmaxf(c[t][nt][r] + hb1v[nt], 0.0f);
                    bufB[(16 * t + quad * 4 + r) * 72 + nt * 16 + l15] = f2b(v);
                }
    }
    LDS_FENCE();   // (4) L3 writes (bufB U) -> L4 reads; orders L4's bufA
                   //     writes after L3's bufA reads

    // ---- L4: U(64) @ H2 -> 64, +hb2, relu -> bufA cols 0..63 (V) ----
    {
        short8 w[8];
#pragma unroll
        for (int f = 0; f < 8; ++f) w[f] = FRAG(10 + f);
        f32x4 c[3][4];
#pragma unroll
        for (int t = 0; t < 3; ++t) {
            const short8 a0 = *(const short8*)&bufB[(16 * t + l15) * 72 + quad * 8];
            const short8 a1 = *(const short8*)&bufB[(16 * t + l15) * 72 + 32 + quad * 8];
#pragma unroll
            for (int nt = 0; nt < 4; ++nt) {
                f32x4 u = MFMA16(a0, w[nt * 2], zero);
                c[t][nt] = MFMA16(a1, w[nt * 2 + 1], u);
            }
        }
#pragma unroll
        for (int t = 0; t < 3; ++t)
#pragma unroll
            for (int nt = 0; nt < 4; ++nt)
#pragma unroll
                for (int r = 0; r < 4; ++r) {
                    const float v = fmaxf(c[t][nt][r] + hb2v[nt], 0.0f);
                    bufA[(16 * t + quad * 4 + r) * 72 + nt * 16 + l15] = f2b(v);
                }
    }
    LDS_FENCE();   // (5) L4 writes (bufA V) -> L5 reads; orders sW writes
                   //     (bufB) after L4's bufB reads

    // ---- L5: V(64) @ H3 -> 3 (cols>=3 zero weights) ----
    f32x4 rgbc[3];
    {
        const short8 w0 = FRAG(18), w1f = FRAG(19);
#pragma unroll
        for (int t = 0; t < 3; ++t) {
            const short8 a0 = *(const short8*)&bufA[(16 * t + l15) * 72 + quad * 8];
            const short8 a1 = *(const short8*)&bufA[(16 * t + l15) * 72 + 32 + quad * 8];
            f32x4 c = MFMA16(a0, w0, zero);
            rgbc[t] = MFMA16(a1, w1f, c);
        }
    }
#undef FRAG

    // ---- softmax over the batch's 48 densities (wave shuffles) ----
    const float d = (lane < NS) ? densities[p0 + lane] : -INFINITY;
    float m = d;
#pragma unroll
    for (int off = 32; off > 0; off >>= 1) m = fmaxf(m, __shfl_xor(m, off));
    const float e = expf(d - m);              // -inf -> 0 for lanes >= 48
    float sum = e;
#pragma unroll
    for (int off = 32; off > 0; off >>= 1) sum += __shfl_xor(sum, off);
    const float wgt = e / sum;

    float* sW = (float*)bufB;                 // bufB dead after L4 reads
    if (lane < NS) sW[lane] = wgt;
    LDS_FENCE();   // (6)+(7) sW write -> sW read

    // ---- weighted sum of sigmoid(rgb): rows held as C-layout frags ----
    float acc = 0.0f;
#pragma unroll
    for (int t = 0; t < 3; ++t)
#pragma unroll
        for (int r = 0; r < 4; ++r) {
            const int row = 16 * t + quad * 4 + r;
            acc += sW[row] * sigmoidf(rgbc[t][r] + hb3v);
        }
    // butterfly over quads (same l15 in lanes {l15, 16+l15, 32+l15, 48+l15})
    acc += __shfl_xor(acc, 16);
    acc += __shfl_xor(acc, 32);
    if (lane < 3) out[bidb * 3 + lane] = acc;
}

extern "C" void kernel_launch(void* const* d_in, const int* in_sizes, int n_in,
                              void* d_out, int out_size, void* d_ws, size_t ws_size,
                              hipStream_t stream) {
    const float* positions = (const float*)d_in[0];
    const float* densities = (const float*)d_in[1];
    const float* normals   = (const float*)d_in[2];
    const float* c2w       = (const float*)d_in[3];
    const float* table     = (const float*)d_in[4];
    const float* w1  = (const float*)d_in[5];
    const float* b1  = (const float*)d_in[6];
    const float* w2  = (const float*)d_in[7];
    const float* b2  = (const float*)d_in[8];
    const float* h1  = (const float*)d_in[9];
    const float* hb1 = (const float*)d_in[10];
    const float* h2  = (const float*)d_in[11];
    const float* hb2 = (const float*)d_in[12];
    const float* h3  = (const float*)d_in[13];
    const float* hb3 = (const float*)d_in[14];
    float* out = (float*)d_out;

    // ws layout: bank (20 KB) | enc (NLEV*NPTS u32 = 12.6 MB)
    ushort*   bank   = (ushort*)d_ws;
    uint32_t* enc_ws = (uint32_t*)((char*)d_ws + 20 * 1024);

    Scales sc;
    const double growth = exp((log(2048.0) - log(16.0)) / 15.0);
    for (int i = 0; i < NLEV; ++i)
        sc.s[i] = (float)floor(16.0 * pow(growth, (double)i));

    prep_bank_kernel<<<1, 256, 0, stream>>>(w1, w2, h1, h2, h3, bank);
    encode_kernel<<<dim3(NPTS / 256, NLEV), 256, 0, stream>>>(
        positions, c2w, table, enc_ws, sc);
    tail_kernel<<<NB, 64, 0, stream>>>(
        enc_ws, densities, normals, c2w, bank, b1, b2, hb1, hb2, hb3, out);
}